// Round 4
// baseline (1053.486 us; speedup 1.0000x reference)
//
#include <hip/hip_runtime.h>
#include <hip/hip_bf16.h>
#include <math.h>

#define S_TOTAL 4096
#define B_TOTAL 4
#define M_TOTAL 16384
#define M2_TOTAL 32768   // q and k batched
#define NSLICE 8

typedef __attribute__((ext_vector_type(8))) short bf16x8;
typedef __attribute__((ext_vector_type(4))) float f32x4;

__device__ __forceinline__ void glds16(const void* src, void* lds_base) {
    __builtin_amdgcn_global_load_lds(
        (const __attribute__((address_space(1))) void*)src,
        (__attribute__((address_space(3))) void*)lds_base, 16, 0, 0);
}

// granule swizzle: keeps 16B-granule accesses spread across bank groups.
// GR = granules per row. GR=4 -> use (row>>1)&3; GR>=8 -> row&7.
__device__ __forceinline__ int swz(int cg, int row, int GR) {
    return (GR == 4) ? (cg ^ ((row >> 1) & 3)) : (cg ^ (row & 7));
}

// ---------------- gather + diff -> bf16 rows [z*M + b*S + s, C]
__global__ __launch_bounds__(64) void gather_diff(
    const float* __restrict__ fq, const float* __restrict__ fk,
    const int* __restrict__ cid, const int* __restrict__ nid,
    __hip_bfloat16* __restrict__ out, int C, int HW)
{
    int s = blockIdx.x, bb = blockIdx.y, z = blockIdx.z;
    int ci = cid[s], ni = nid[s];
    const float* fb = (z ? fk : fq) + (size_t)bb * C * HW;
    __hip_bfloat16* o = out + ((size_t)z * M_TOTAL + (size_t)bb * S_TOTAL + s) * C;
    for (int c = threadIdx.x; c < C; c += 64)
        o[c] = __float2bfloat16(fb[(size_t)c * HW + ci] - fb[(size_t)c * HW + ni]);
}

// ---------------- fp32 -> bf16 weight conversion (12 matrices, one kernel)
struct WArgs { const float* s[12]; __hip_bfloat16* d[12]; int n[12]; };
__global__ __launch_bounds__(256) void convert_w(WArgs a) {
    int mtx = blockIdx.y, n = a.n[mtx];
    const float* s = a.s[mtx];
    __hip_bfloat16* d = a.d[mtx];
    for (int i = blockIdx.x * 256 + threadIdx.x; i < n; i += gridDim.x * 256)
        d[i] = __float2bfloat16(s[i]);
}

// ---------------- bf16 MFMA GEMM: Y[M,N] = act(X[M,K] @ W[N,K]^T + bias)
// 128 x BN block tile, BK=32, 4 waves, 16x16x32 bf16 MFMA, swizzled LDS.
template<int BN>
__global__ __launch_bounds__(256) void gemm_mfma(
    const __hip_bfloat16* __restrict__ X, const __hip_bfloat16* __restrict__ W,
    const float* __restrict__ bias, __hip_bfloat16* __restrict__ Y,
    int K, int ldY, int relu)
{
    constexpr int WN = (BN == 128) ? 2 : 1;
    constexpr int WM = 4 / WN;
    constexpr int RM = 128 / WM;
    constexpr int RN = BN / WN;
    constexpr int TMI = RM / 16, TNI = RN / 16;
    __shared__ __hip_bfloat16 As[128 * 32];
    __shared__ __hip_bfloat16 Bs[BN * 32];
    const int lane = threadIdx.x & 63, wave = threadIdx.x >> 6;
    const int quad = lane >> 4, l15 = lane & 15;
    const int wm = wave % WM, wn = wave / WM;
    const int m0 = blockIdx.y * 128, n0 = blockIdx.x * BN;

    f32x4 acc[TMI][TNI];
#pragma unroll
    for (int i = 0; i < TMI; ++i)
#pragma unroll
        for (int j = 0; j < TNI; ++j) acc[i][j] = (f32x4){0.f, 0.f, 0.f, 0.f};

    for (int k0 = 0; k0 < K; k0 += 32) {
        // stage A: 128x32 (GR=4, 512 granules), source col-granule swizzled
        for (int h = 0; h < 2; ++h) {
            int g0 = h * 256 + wave * 64;
            int g = g0 + lane;
            int row = g >> 2, cg = g & 3;
            glds16(X + (size_t)(m0 + row) * K + k0 + swz(cg, row, 4) * 8,
                   (char*)As + g0 * 16);
        }
        for (int g0 = wave * 64; g0 < BN * 4; g0 += 256) {
            int g = g0 + lane;
            int row = g >> 2, cg = g & 3;
            glds16(W + (size_t)(n0 + row) * K + k0 + swz(cg, row, 4) * 8,
                   (char*)Bs + g0 * 16);
        }
        __syncthreads();
        bf16x8 af[TMI], bfr[TNI];
#pragma unroll
        for (int i = 0; i < TMI; ++i) {
            int row = wm * RM + i * 16 + l15;
            af[i] = *(const bf16x8*)(As + row * 32 + swz(quad, row, 4) * 8);
        }
#pragma unroll
        for (int j = 0; j < TNI; ++j) {
            int row = wn * RN + j * 16 + l15;
            bfr[j] = *(const bf16x8*)(Bs + row * 32 + swz(quad, row, 4) * 8);
        }
#pragma unroll
        for (int i = 0; i < TMI; ++i)
#pragma unroll
            for (int j = 0; j < TNI; ++j)
                acc[i][j] = __builtin_amdgcn_mfma_f32_16x16x32_bf16(
                    af[i], bfr[j], acc[i][j], 0, 0, 0);
        __syncthreads();
    }

#pragma unroll
    for (int j = 0; j < TNI; ++j) {
        int col = n0 + wn * RN + j * 16 + l15;
        float bv = bias[col];
#pragma unroll
        for (int i = 0; i < TMI; ++i) {
            int row = m0 + wm * RM + i * 16 + quad * 4;
#pragma unroll
            for (int r = 0; r < 4; ++r) {
                float v = acc[i][j][r] + bv;
                if (relu) v = fmaxf(v, 0.f);
                Y[(size_t)(row + r) * ldY + col] = __float2bfloat16(v);
            }
        }
    }
}

// ---------------- MFMA NCE: 64-row x 128-col score tiles, flash LSE (base-2).
// Q fragments in REGISTERS (loaded from global in A-layout); only K in LDS
// (swizzled). 4 waves each own a 32-col group. Partials per (slice, wave).
template<int KPAD>
__global__ __launch_bounds__(256, 3) void nce_mfma(
    const __hip_bfloat16* __restrict__ Fq, const __hip_bfloat16* __restrict__ Fk,
    float2* __restrict__ partial, float s2)
{
    constexpr int KS = KPAD / 32;
    constexpr int GR = KPAD / 8;
    __shared__ __hip_bfloat16 Ks[128 * KPAD];
    const int lane = threadIdx.x & 63, wave = threadIdx.x >> 6;
    const int quad = lane >> 4, l15 = lane & 15;
    const int wn = wave;
    const int bb = blockIdx.z, slice = blockIdx.y, r0 = blockIdx.x * 64;

    // Q fragments, rows r0..r0+63 (A-layout: lane l15 = row, quad*8 = k chunk)
    bf16x8 qf[4][KS];
    const __hip_bfloat16* Qb = Fq + ((size_t)bb * S_TOTAL + r0) * KPAD;
#pragma unroll
    for (int i = 0; i < 4; ++i)
#pragma unroll
        for (int s = 0; s < KS; ++s)
            qf[i][s] = *(const bf16x8*)(Qb + (size_t)(i * 16 + l15) * KPAD + s * 32 + quad * 8);

    float m[16], l[16];
#pragma unroll
    for (int i = 0; i < 16; ++i) { m[i] = -1e30f; l[i] = 0.f; }

    const int t_begin = slice * (S_TOTAL / NSLICE);
    for (int t0 = t_begin; t0 < t_begin + S_TOTAL / NSLICE; t0 += 128) {
        __syncthreads();   // previous tile's readers done
        const __hip_bfloat16* Kb = Fk + ((size_t)bb * S_TOTAL + t0) * KPAD;
        for (int g0 = wave * 64; g0 < 128 * GR; g0 += 256) {
            int g = g0 + lane;
            int row = g / GR, cg = g % GR;
            glds16(Kb + (size_t)row * KPAD + swz(cg, row, GR) * 8,
                   (char*)Ks + g0 * 16);
        }
        __syncthreads();

        f32x4 acc[4][2];
#pragma unroll
        for (int i = 0; i < 4; ++i)
#pragma unroll
            for (int j = 0; j < 2; ++j) acc[i][j] = (f32x4){0.f, 0.f, 0.f, 0.f};

#pragma unroll
        for (int s = 0; s < KS; ++s) {
            bf16x8 bfr[2];
#pragma unroll
            for (int j = 0; j < 2; ++j) {
                int row = wn * 32 + j * 16 + l15;
                bfr[j] = *(const bf16x8*)(Ks + (size_t)row * KPAD + swz(s * 4 + quad, row, GR) * 8);
            }
#pragma unroll
            for (int i = 0; i < 4; ++i)
#pragma unroll
                for (int j = 0; j < 2; ++j)
                    acc[i][j] = __builtin_amdgcn_mfma_f32_16x16x32_bf16(
                        qf[i][s], bfr[j], acc[i][j], 0, 0, 0);
        }

        // online softmax (base-2; scale folded into the fma)
#pragma unroll
        for (int i = 0; i < 4; ++i)
#pragma unroll
            for (int r = 0; r < 4; ++r) {
                int idx = i * 4 + r;
                float v0 = acc[i][0][r], v1 = acc[i][1][r];
                float mn = fmaxf(m[idx], fmaxf(v0, v1));
                float ms = mn * s2;
                float lv = l[idx] * exp2f(fmaf(m[idx], s2, -ms));
                lv += exp2f(fmaf(v0, s2, -ms)) + exp2f(fmaf(v1, s2, -ms));
                m[idx] = mn; l[idx] = lv;
            }
    }

    // merge across the 16 col-lanes
#pragma unroll
    for (int off = 1; off < 16; off <<= 1)
#pragma unroll
        for (int i = 0; i < 16; ++i) {
            float mo = __shfl_xor(m[i], off);
            float lo = __shfl_xor(l[i], off);
            float mn = fmaxf(m[i], mo);
            l[i] = l[i] * exp2f((m[i] - mn) * s2) + lo * exp2f((mo - mn) * s2);
            m[i] = mn;
        }
    if (l15 == 0) {
        size_t base = (size_t)((bb * NSLICE + slice) * 4 + wn) * S_TOTAL;
#pragma unroll
        for (int i = 0; i < 4; ++i)
#pragma unroll
            for (int r = 0; r < 4; ++r) {
                int row = r0 + i * 16 + quad * 4 + r;
                partial[base + row] = make_float2(m[i * 4 + r], l[i * 4 + r]);
            }
    }
}

// ---------------- merge partials + pos diagonal -> loss
__global__ __launch_bounds__(256) void nce_reduce(
    const __hip_bfloat16* __restrict__ Fq, const __hip_bfloat16* __restrict__ Fk,
    const float2* __restrict__ partial, float* __restrict__ out,
    int KPAD, float s2, float inv_tau)
{
    __shared__ float red[4];
    const int tid = threadIdx.x;
    const int g = blockIdx.x * 256 + tid;
    const int bb = g >> 12, s = g & 4095;

    float M = -1e30f, L = 0.f;
    for (int p = 0; p < NSLICE * 4; ++p) {
        float2 pr = partial[(size_t)(bb * NSLICE * 4 + p) * S_TOTAL + s];
        float mn = fmaxf(M, pr.x);
        L = L * exp2f((M - mn) * s2) + pr.y * exp2f((pr.x - mn) * s2);
        M = mn;
    }
    const __hip_bfloat16* q = Fq + (size_t)g * KPAD;
    const __hip_bfloat16* k = Fk + (size_t)g * KPAD;
    float pos = 0.f;
    for (int c = 0; c < KPAD; ++c)
        pos += __bfloat162float(q[c]) * __bfloat162float(k[c]);
    float v = 0.6931471805599453f * (M * s2 + log2f(L)) - pos * inv_tau;
#pragma unroll
    for (int off = 1; off < 64; off <<= 1) v += __shfl_xor(v, off);
    if ((tid & 63) == 0) red[tid >> 6] = v;
    __syncthreads();
    if (tid == 0)
        atomicAdd(out, (red[0] + red[1] + red[2] + red[3]) * (1.0f / (float)M_TOTAL));
}

// ---------------- GEMM dispatch (M = 32768 rows always)
static void launch_gemm(const __hip_bfloat16* X, const __hip_bfloat16* W,
                        const float* bias, __hip_bfloat16* Y,
                        int N, int K, int ldY, int relu, hipStream_t st)
{
    const int gy = M2_TOTAL / 128;
    if (N >= 256)
        gemm_mfma<128><<<dim3(N / 128, gy), 256, 0, st>>>(X, W, bias, Y, K, ldY, relu);
    else if (N == 128)
        gemm_mfma<64><<<dim3(2, gy), 256, 0, st>>>(X, W, bias, Y, K, ldY, relu);
    else if (N == 64)
        gemm_mfma<64><<<dim3(1, gy), 256, 0, st>>>(X, W, bias, Y, K, ldY, relu);
    else if (N == 32)
        gemm_mfma<32><<<dim3(1, gy), 256, 0, st>>>(X, W, bias, Y, K, ldY, relu);
    else
        gemm_mfma<16><<<dim3(1, gy), 256, 0, st>>>(X, W, bias, Y, K, ldY, relu);
}

// ---------------- orchestration
extern "C" void kernel_launch(void* const* d_in, const int* in_sizes, int n_in,
                              void* d_out, int out_size, void* d_ws, size_t ws_size,
                              hipStream_t stream)
{
    (void)in_sizes; (void)n_in; (void)out_size; (void)ws_size;
    hipMemsetAsync(d_out, 0, sizeof(float), stream);

    static const int Cs[4]  = {64, 128, 256, 512};
    static const int HWs[4] = {256 * 256, 128 * 128, 64 * 64, 32 * 32};
    const float s2 = 144.26950408889634f;   // (1/tau) * log2(e)

    // workspace carve (~77 MB): Xb/Yb are the batched activation ping-pong;
    // partial aliases Yb (Yb idle during nce).
    char* p = (char*)d_ws;
    __hip_bfloat16* Xb = (__hip_bfloat16*)p; p += (size_t)M2_TOTAL * 512 * 2;
    __hip_bfloat16* Yb = (__hip_bfloat16*)p; p += (size_t)M2_TOTAL * 512 * 2;
    __hip_bfloat16* F  = (__hip_bfloat16*)p; p += (size_t)M2_TOTAL * 128 * 2;
    __hip_bfloat16* wb = (__hip_bfloat16*)p;
    float2* partial = (float2*)Yb;

    WArgs wa;
    size_t off = 0;
    for (int i = 0; i < 4; ++i)
        for (int j = 0; j < 3; ++j) {
            int N = (j == 2) ? Cs[i] / 4 : Cs[i];
            int K = Cs[i];
            wa.s[i * 3 + j] = (const float*)d_in[i * 10 + 4 + j * 2];
            wa.d[i * 3 + j] = wb + off;
            wa.n[i * 3 + j] = N * K;
            off += (size_t)N * K;
        }
    convert_w<<<dim3(64, 12), 256, 0, stream>>>(wa);

    for (int i = 0; i < 4; ++i) {
        const int C = Cs[i], HW = HWs[i], Cout = C / 4;
        const int Kpad = (Cout < 32) ? 32 : Cout;
        const float* fq  = (const float*)d_in[i * 10 + 0];
        const float* fk  = (const float*)d_in[i * 10 + 1];
        const int*   cid = (const int*)  d_in[i * 10 + 2];
        const int*   nid = (const int*)  d_in[i * 10 + 3];
        const float* b0  = (const float*)d_in[i * 10 + 5];
        const float* b1  = (const float*)d_in[i * 10 + 7];
        const float* b2  = (const float*)d_in[i * 10 + 9];

        if (Kpad > Cout)   // zero-pad feature cols (layer 0 only)
            hipMemsetAsync(F, 0, (size_t)M2_TOTAL * Kpad * 2, stream);

        gather_diff<<<dim3(S_TOTAL, B_TOTAL, 2), 64, 0, stream>>>(
            fq, fk, cid, nid, Xb, C, HW);
        launch_gemm(Xb, wa.d[i * 3 + 0], b0, Yb, C, C, C, 1, stream);
        launch_gemm(Yb, wa.d[i * 3 + 1], b1, Xb, C, C, C, 1, stream);
        launch_gemm(Xb, wa.d[i * 3 + 2], b2, F, Cout, C, Kpad, 0, stream);

        const __hip_bfloat16* Fq = F;
        const __hip_bfloat16* Fk = F + (size_t)M_TOTAL * Kpad;
        dim3 ngrid(S_TOTAL / 64, NSLICE, B_TOTAL);
        if (Kpad == 32)
            nce_mfma<32><<<ngrid, 256, 0, stream>>>(Fq, Fk, partial, s2);
        else if (Kpad == 64)
            nce_mfma<64><<<ngrid, 256, 0, stream>>>(Fq, Fk, partial, s2);
        else
            nce_mfma<128><<<ngrid, 256, 0, stream>>>(Fq, Fk, partial, s2);

        nce_reduce<<<dim3(M_TOTAL / 256), 256, 0, stream>>>(
            Fq, Fk, partial, (float*)d_out, Kpad, s2, 100.0f);
    }
}

// Round 5
// 961.585 us; speedup vs baseline: 1.0956x; 1.0956x over previous
//
#include <hip/hip_runtime.h>
#include <hip/hip_bf16.h>
#include <math.h>

#define S_TOTAL 4096
#define B_TOTAL 4
#define M_TOTAL 16384
#define M2_TOTAL 32768   // q and k batched
#define NSLICE 8

typedef __attribute__((ext_vector_type(8))) short bf16x8;
typedef __attribute__((ext_vector_type(4))) float f32x4;

__device__ __forceinline__ void glds16(const void* src, void* lds_base) {
    __builtin_amdgcn_global_load_lds(
        (const __attribute__((address_space(1))) void*)src,
        (__attribute__((address_space(3))) void*)lds_base, 16, 0, 0);
}

// granule swizzle: spread 16B granules across bank groups.
__device__ __forceinline__ int swz(int cg, int row, int GR) {
    return (GR == 4) ? (cg ^ ((row >> 1) & 3)) : (cg ^ (row & 7));
}

// ---------------- fp32 -> bf16 weight conversion (12 matrices, one kernel)
struct WArgs { const float* s[12]; __hip_bfloat16* d[12]; int n[12]; };
__global__ __launch_bounds__(256) void convert_w(WArgs a) {
    int mtx = blockIdx.y, n = a.n[mtx];
    const float* s = a.s[mtx];
    __hip_bfloat16* d = a.d[mtx];
    for (int i = blockIdx.x * 256 + threadIdx.x; i < n; i += gridDim.x * 256)
        d[i] = __float2bfloat16(s[i]);
}

// ---------------- full-map GEMM0: U[b, hw, n] = sum_c feat[b, c, hw] * W0[n, c]
// A is feat (fp32, channel-major): fragments loaded DIRECTLY from global —
// lane l15 spans contiguous hw (coalesced 64B per quad-group), quad spans c.
// Only W0 staged in LDS. Output pixel-major bf16 so the gather is contiguous.
template<int BN>
__global__ __launch_bounds__(256) void gemm_map(
    const float* __restrict__ feat,       // [B, K, HW] (this z)
    const __hip_bfloat16* __restrict__ W, // [N=K, K] bf16
    __hip_bfloat16* __restrict__ U,       // [B, HW, N]
    int K, int HW)
{
    constexpr int WN = (BN == 128) ? 2 : 1;
    constexpr int WM = 4 / WN;
    constexpr int RM = 128 / WM, RN = BN / WN;
    constexpr int TMI = RM / 16, TNI = RN / 16;
    __shared__ __hip_bfloat16 Bs[BN * 32];
    const int lane = threadIdx.x & 63, wave = threadIdx.x >> 6;
    const int quad = lane >> 4, l15 = lane & 15;
    const int wm = wave % WM, wn = wave / WM;
    const int m0 = blockIdx.y * 128, n0 = blockIdx.x * BN;
    const int b = blockIdx.z;
    const float* Ab = feat + (size_t)b * K * HW;

    f32x4 acc[TMI][TNI];
#pragma unroll
    for (int i = 0; i < TMI; ++i)
#pragma unroll
        for (int j = 0; j < TNI; ++j) acc[i][j] = (f32x4){0.f, 0.f, 0.f, 0.f};

    for (int k0 = 0; k0 < K; k0 += 32) {
        for (int g0 = wave * 64; g0 < BN * 4; g0 += 256) {
            int g = g0 + lane, row = g >> 2, cg = g & 3;
            glds16(W + (size_t)(n0 + row) * K + k0 + swz(cg, row, 4) * 8,
                   (char*)Bs + g0 * 16);
        }
        __syncthreads();
        bf16x8 af[TMI];
#pragma unroll
        for (int i = 0; i < TMI; ++i) {
            const float* ap = Ab + (size_t)(k0 + quad * 8) * HW
                            + (m0 + wm * RM + i * 16 + l15);
#pragma unroll
            for (int j = 0; j < 8; ++j) {
                __hip_bfloat16 h = __float2bfloat16(ap[(size_t)j * HW]);
                af[i][j] = *(short*)&h;
            }
        }
        bf16x8 bfr[TNI];
#pragma unroll
        for (int j = 0; j < TNI; ++j) {
            int row = wn * RN + j * 16 + l15;
            bfr[j] = *(const bf16x8*)(Bs + row * 32 + swz(quad, row, 4) * 8);
        }
#pragma unroll
        for (int i = 0; i < TMI; ++i)
#pragma unroll
            for (int j = 0; j < TNI; ++j)
                acc[i][j] = __builtin_amdgcn_mfma_f32_16x16x32_bf16(
                    af[i], bfr[j], acc[i][j], 0, 0, 0);
        __syncthreads();
    }
#pragma unroll
    for (int j = 0; j < TNI; ++j) {
        int col = n0 + wn * RN + j * 16 + l15;
#pragma unroll
        for (int i = 0; i < TMI; ++i) {
            int row = m0 + wm * RM + i * 16 + quad * 4;
#pragma unroll
            for (int r = 0; r < 4; ++r)
                U[((size_t)b * HW + row + r) * K + col] = __float2bfloat16(acc[i][j][r]);
        }
    }
}

// ---------------- gather2: X[z*M + r] = relu(U[cid] - U[nid] + b0), contiguous rows
__global__ __launch_bounds__(256) void gather2(
    const __hip_bfloat16* __restrict__ U, const int* __restrict__ cid,
    const int* __restrict__ nid, const float* __restrict__ b0,
    __hip_bfloat16* __restrict__ X, int C, int HW, int z)
{
    int wv = threadIdx.x >> 6, lane = threadIdx.x & 63;
    int r = blockIdx.x * 4 + wv;            // 0..16383
    int s = r & 4095, b = r >> 12;
    int ci = cid[s], ni = nid[s];
    const __hip_bfloat16* up = U + ((size_t)b * HW + ci) * C;
    const __hip_bfloat16* un = U + ((size_t)b * HW + ni) * C;
    __hip_bfloat16* xo = X + ((size_t)z * M_TOTAL + r) * C;
    for (int c = lane; c < C; c += 64) {
        float v = __bfloat162float(up[c]) - __bfloat162float(un[c]) + b0[c];
        xo[c] = __float2bfloat16(fmaxf(v, 0.f));
    }
}

// ---------------- bf16 MFMA GEMM: Y[M,N] = act(X[M,K] @ W[N,K]^T + bias)
template<int BN>
__global__ __launch_bounds__(256) void gemm_mfma(
    const __hip_bfloat16* __restrict__ X, const __hip_bfloat16* __restrict__ W,
    const float* __restrict__ bias, __hip_bfloat16* __restrict__ Y,
    int K, int ldY, int relu)
{
    constexpr int WN = (BN == 128) ? 2 : 1;
    constexpr int WM = 4 / WN;
    constexpr int RM = 128 / WM, RN = BN / WN;
    constexpr int TMI = RM / 16, TNI = RN / 16;
    __shared__ __hip_bfloat16 As[128 * 32];
    __shared__ __hip_bfloat16 Bs[BN * 32];
    const int lane = threadIdx.x & 63, wave = threadIdx.x >> 6;
    const int quad = lane >> 4, l15 = lane & 15;
    const int wm = wave % WM, wn = wave / WM;
    const int m0 = blockIdx.y * 128, n0 = blockIdx.x * BN;

    f32x4 acc[TMI][TNI];
#pragma unroll
    for (int i = 0; i < TMI; ++i)
#pragma unroll
        for (int j = 0; j < TNI; ++j) acc[i][j] = (f32x4){0.f, 0.f, 0.f, 0.f};

    for (int k0 = 0; k0 < K; k0 += 32) {
        for (int h = 0; h < 2; ++h) {
            int g0 = h * 256 + wave * 64;
            int g = g0 + lane, row = g >> 2, cg = g & 3;
            glds16(X + (size_t)(m0 + row) * K + k0 + swz(cg, row, 4) * 8,
                   (char*)As + g0 * 16);
        }
        for (int g0 = wave * 64; g0 < BN * 4; g0 += 256) {
            int g = g0 + lane, row = g >> 2, cg = g & 3;
            glds16(W + (size_t)(n0 + row) * K + k0 + swz(cg, row, 4) * 8,
                   (char*)Bs + g0 * 16);
        }
        __syncthreads();
        bf16x8 af[TMI], bfr[TNI];
#pragma unroll
        for (int i = 0; i < TMI; ++i) {
            int row = wm * RM + i * 16 + l15;
            af[i] = *(const bf16x8*)(As + row * 32 + swz(quad, row, 4) * 8);
        }
#pragma unroll
        for (int j = 0; j < TNI; ++j) {
            int row = wn * RN + j * 16 + l15;
            bfr[j] = *(const bf16x8*)(Bs + row * 32 + swz(quad, row, 4) * 8);
        }
#pragma unroll
        for (int i = 0; i < TMI; ++i)
#pragma unroll
            for (int j = 0; j < TNI; ++j)
                acc[i][j] = __builtin_amdgcn_mfma_f32_16x16x32_bf16(
                    af[i], bfr[j], acc[i][j], 0, 0, 0);
        __syncthreads();
    }

#pragma unroll
    for (int j = 0; j < TNI; ++j) {
        int col = n0 + wn * RN + j * 16 + l15;
        float bv = bias[col];
#pragma unroll
        for (int i = 0; i < TMI; ++i) {
            int row = m0 + wm * RM + i * 16 + quad * 4;
#pragma unroll
            for (int r = 0; r < 4; ++r) {
                float v = acc[i][j][r] + bv;
                if (relu) v = fmaxf(v, 0.f);
                Y[(size_t)(row + r) * ldY + col] = __float2bfloat16(v);
            }
        }
    }
}

// ---------------- MFMA NCE: 64-row x 128-col score tiles, flash LSE (base-2).
// Q fragments in registers; K in LDS (swizzled). Partials per (slice, wave).
template<int KPAD, int MINW>
__global__ __launch_bounds__(256, MINW) void nce_mfma(
    const __hip_bfloat16* __restrict__ Fq, const __hip_bfloat16* __restrict__ Fk,
    float2* __restrict__ partial, float s2)
{
    constexpr int KS = KPAD / 32;
    constexpr int GR = KPAD / 8;
    __shared__ __hip_bfloat16 Ks[128 * KPAD];
    const int lane = threadIdx.x & 63, wave = threadIdx.x >> 6;
    const int quad = lane >> 4, l15 = lane & 15;
    const int wn = wave;
    const int bb = blockIdx.z, slice = blockIdx.y, r0 = blockIdx.x * 64;

    bf16x8 qf[4][KS];
    const __hip_bfloat16* Qb = Fq + ((size_t)bb * S_TOTAL + r0) * KPAD;
#pragma unroll
    for (int i = 0; i < 4; ++i)
#pragma unroll
        for (int s = 0; s < KS; ++s)
            qf[i][s] = *(const bf16x8*)(Qb + (size_t)(i * 16 + l15) * KPAD + s * 32 + quad * 8);

    float m[16], l[16];
#pragma unroll
    for (int i = 0; i < 16; ++i) { m[i] = -1e30f; l[i] = 0.f; }

    const int t_begin = slice * (S_TOTAL / NSLICE);
    for (int t0 = t_begin; t0 < t_begin + S_TOTAL / NSLICE; t0 += 128) {
        __syncthreads();
        const __hip_bfloat16* Kb = Fk + ((size_t)bb * S_TOTAL + t0) * KPAD;
        for (int g0 = wave * 64; g0 < 128 * GR; g0 += 256) {
            int g = g0 + lane, row = g / GR, cg = g % GR;
            glds16(Kb + (size_t)row * KPAD + swz(cg, row, GR) * 8,
                   (char*)Ks + g0 * 16);
        }
        __syncthreads();

        f32x4 acc[4][2];
#pragma unroll
        for (int i = 0; i < 4; ++i)
#pragma unroll
            for (int j = 0; j < 2; ++j) acc[i][j] = (f32x4){0.f, 0.f, 0.f, 0.f};

#pragma unroll
        for (int s = 0; s < KS; ++s) {
            bf16x8 bfr[2];
#pragma unroll
            for (int j = 0; j < 2; ++j) {
                int row = wn * 32 + j * 16 + l15;
                bfr[j] = *(const bf16x8*)(Ks + (size_t)row * KPAD + swz(s * 4 + quad, row, GR) * 8);
            }
#pragma unroll
            for (int i = 0; i < 4; ++i)
#pragma unroll
                for (int j = 0; j < 2; ++j)
                    acc[i][j] = __builtin_amdgcn_mfma_f32_16x16x32_bf16(
                        qf[i][s], bfr[j], acc[i][j], 0, 0, 0);
        }

#pragma unroll
        for (int i = 0; i < 4; ++i)
#pragma unroll
            for (int r = 0; r < 4; ++r) {
                int idx = i * 4 + r;
                float v0 = acc[i][0][r], v1 = acc[i][1][r];
                float mn = fmaxf(m[idx], fmaxf(v0, v1));
                float ms = mn * s2;
                float lv = l[idx] * exp2f(fmaf(m[idx], s2, -ms));
                lv += exp2f(fmaf(v0, s2, -ms)) + exp2f(fmaf(v1, s2, -ms));
                m[idx] = mn; l[idx] = lv;
            }
    }

#pragma unroll
    for (int off = 1; off < 16; off <<= 1)
#pragma unroll
        for (int i = 0; i < 16; ++i) {
            float mo = __shfl_xor(m[i], off);
            float lo = __shfl_xor(l[i], off);
            float mn = fmaxf(m[i], mo);
            l[i] = l[i] * exp2f((m[i] - mn) * s2) + lo * exp2f((mo - mn) * s2);
            m[i] = mn;
        }
    if (l15 == 0) {
        size_t base = (size_t)((bb * NSLICE + slice) * 4 + wn) * S_TOTAL;
#pragma unroll
        for (int i = 0; i < 4; ++i)
#pragma unroll
            for (int r = 0; r < 4; ++r) {
                int row = r0 + i * 16 + quad * 4 + r;
                partial[base + row] = make_float2(m[i * 4 + r], l[i * 4 + r]);
            }
    }
}

// ---------------- merge partials + pos diagonal -> loss
__global__ __launch_bounds__(256) void nce_reduce(
    const __hip_bfloat16* __restrict__ Fq, const __hip_bfloat16* __restrict__ Fk,
    const float2* __restrict__ partial, float* __restrict__ out,
    int KPAD, float s2, float inv_tau)
{
    __shared__ float red[4];
    const int tid = threadIdx.x;
    const int g = blockIdx.x * 256 + tid;
    const int bb = g >> 12, s = g & 4095;

    float M = -1e30f, L = 0.f;
    for (int p = 0; p < NSLICE * 4; ++p) {
        float2 pr = partial[(size_t)(bb * NSLICE * 4 + p) * S_TOTAL + s];
        float mn = fmaxf(M, pr.x);
        L = L * exp2f((M - mn) * s2) + pr.y * exp2f((pr.x - mn) * s2);
        M = mn;
    }
    const __hip_bfloat16* q = Fq + (size_t)g * KPAD;
    const __hip_bfloat16* k = Fk + (size_t)g * KPAD;
    float pos = 0.f;
    for (int c = 0; c < KPAD; ++c)
        pos += __bfloat162float(q[c]) * __bfloat162float(k[c]);
    float v = 0.6931471805599453f * (M * s2 + log2f(L)) - pos * inv_tau;
#pragma unroll
    for (int off = 1; off < 64; off <<= 1) v += __shfl_xor(v, off);
    if ((tid & 63) == 0) red[tid >> 6] = v;
    __syncthreads();
    if (tid == 0)
        atomicAdd(out, (red[0] + red[1] + red[2] + red[3]) * (1.0f / (float)M_TOTAL));
}

// ---------------- dispatch helpers
static void launch_gemm(const __hip_bfloat16* X, const __hip_bfloat16* W,
                        const float* bias, __hip_bfloat16* Y,
                        int N, int K, int ldY, int relu, hipStream_t st)
{
    const int gy = M2_TOTAL / 128;
    if (N >= 128)
        gemm_mfma<128><<<dim3(N / 128, gy), 256, 0, st>>>(X, W, bias, Y, K, ldY, relu);
    else if (N == 64)
        gemm_mfma<64><<<dim3(1, gy), 256, 0, st>>>(X, W, bias, Y, K, ldY, relu);
    else if (N == 32)
        gemm_mfma<32><<<dim3(1, gy), 256, 0, st>>>(X, W, bias, Y, K, ldY, relu);
    else
        gemm_mfma<16><<<dim3(1, gy), 256, 0, st>>>(X, W, bias, Y, K, ldY, relu);
}

static void launch_map(const float* feat, const __hip_bfloat16* W0,
                       __hip_bfloat16* U, int C, int HW, hipStream_t st)
{
    if (C >= 128)
        gemm_map<128><<<dim3(C / 128, HW / 128, B_TOTAL), 256, 0, st>>>(feat, W0, U, C, HW);
    else
        gemm_map<64><<<dim3(1, HW / 128, B_TOTAL), 256, 0, st>>>(feat, W0, U, C, HW);
}

// ---------------- orchestration
extern "C" void kernel_launch(void* const* d_in, const int* in_sizes, int n_in,
                              void* d_out, int out_size, void* d_ws, size_t ws_size,
                              hipStream_t stream)
{
    (void)in_sizes; (void)n_in; (void)out_size; (void)ws_size;
    hipMemsetAsync(d_out, 0, sizeof(float), stream);

    static const int Cs[4]  = {64, 128, 256, 512};
    static const int HWs[4] = {256 * 256, 128 * 128, 64 * 64, 32 * 32};
    const float s2 = 144.26950408889634f;   // (1/tau) * log2(e)

    // workspace (~74 MB): region1 holds U (per-z, <=32MiB) then Yb (32MiB) then partial
    char* p = (char*)d_ws;
    char* region1 = p;                       p += (size_t)32 * 1024 * 1024;
    __hip_bfloat16* Xb = (__hip_bfloat16*)p; p += (size_t)M2_TOTAL * 512 * 2;
    __hip_bfloat16* F  = (__hip_bfloat16*)p; p += (size_t)M2_TOTAL * 128 * 2;
    __hip_bfloat16* wb = (__hip_bfloat16*)p;
    __hip_bfloat16* U  = (__hip_bfloat16*)region1;
    __hip_bfloat16* Yb = (__hip_bfloat16*)region1;
    float2* partial    = (float2*)region1;

    WArgs wa;
    size_t off = 0;
    for (int i = 0; i < 4; ++i)
        for (int j = 0; j < 3; ++j) {
            int N = (j == 2) ? Cs[i] / 4 : Cs[i];
            int K = Cs[i];
            wa.s[i * 3 + j] = (const float*)d_in[i * 10 + 4 + j * 2];
            wa.d[i * 3 + j] = wb + off;
            wa.n[i * 3 + j] = N * K;
            off += (size_t)N * K;
        }
    convert_w<<<dim3(64, 12), 256, 0, stream>>>(wa);

    for (int i = 0; i < 4; ++i) {
        const int C = Cs[i], HW = HWs[i], Cout = C / 4;
        const int Kpad = (Cout < 32) ? 32 : Cout;
        const float* fq  = (const float*)d_in[i * 10 + 0];
        const float* fk  = (const float*)d_in[i * 10 + 1];
        const int*   cid = (const int*)  d_in[i * 10 + 2];
        const int*   nid = (const int*)  d_in[i * 10 + 3];
        const float* b0  = (const float*)d_in[i * 10 + 5];
        const float* b1  = (const float*)d_in[i * 10 + 7];
        const float* b2  = (const float*)d_in[i * 10 + 9];

        if (Kpad > Cout)   // zero-pad feature cols (layer 0 only)
            hipMemsetAsync(F, 0, (size_t)M2_TOTAL * Kpad * 2, stream);

        // per-z: full-map GEMM0 (pixel-major U), then contiguous gather
        for (int z = 0; z < 2; ++z) {
            launch_map(z ? fk : fq, wa.d[i * 3 + 0], U, C, HW, stream);
            gather2<<<dim3(M_TOTAL / 4), 256, 0, stream>>>(
                U, cid, nid, b0, Xb, C, HW, z);
        }
        launch_gemm(Xb, wa.d[i * 3 + 1], b1, Yb, C, C, C, 1, stream);
        launch_gemm(Yb, wa.d[i * 3 + 2], b2, F, Cout, C, Kpad, 0, stream);

        const __hip_bfloat16* Fq = F;
        const __hip_bfloat16* Fk = F + (size_t)M_TOTAL * Kpad;
        dim3 ngrid(S_TOTAL / 64, NSLICE, B_TOTAL);
        if (Kpad == 32)
            nce_mfma<32, 3><<<ngrid, 256, 0, stream>>>(Fq, Fk, partial, s2);
        else if (Kpad == 64)
            nce_mfma<64, 3><<<ngrid, 256, 0, stream>>>(Fq, Fk, partial, s2);
        else
            nce_mfma<128, 2><<<ngrid, 256, 0, stream>>>(Fq, Fk, partial, s2);

        nce_reduce<<<dim3(M_TOTAL / 256), 256, 0, stream>>>(
            Fq, Fk, partial, (float*)d_out, Kpad, s2, 100.0f);
    }
}